// Round 1
// baseline (9424.002 us; speedup 1.0000x reference)
//
#include <hip/hip_runtime.h>
#include <cstddef>

// ---------------------------------------------------------------------------
// RNNModel: 2-layer LSTM LM. Round 1: correct fp32 baseline.
//   decoded = LSTM2(concat(word_emb, seq_emb)) @ dec_W^T + dec_b
// Scratch strategy:
//   - d_out decoded region (409.6 MB) used as scratch with clobber-safe layout
//   - hs1 in d_ws when ws_size >= 13.1 MB (path A, batched decoder),
//     else per-timestep decode (path B, zero ws required)
// ---------------------------------------------------------------------------

static constexpr int T_ = 50, B_ = 64, E_ = 1024, H_ = 1024, V_ = 32000;
static constexpr int G_ = 4096; // 4*H

__global__ void fill_zero(float* p, int n) {
  int i = blockIdx.x * blockDim.x + threadIdx.x;
  if (i < n) p[i] = 0.f;
}

__global__ void vec_add(float* dst, const float* a, const float* b, int n) {
  int i = blockIdx.x * blockDim.x + threadIdx.x;
  if (i < n) dst[i] = a[i] + b[i];
}

// C[M,N] = A[M,K] @ W[N,K]^T (+bias[N]) (+Dadd[row,N])
// A rows optionally gathered via Aidx (row = Aidx[m]).
// Dadd row = (dmask < 0) ? m : (m & dmask)   (dmask=63 broadcasts y_w over t)
template<int BM, int BN, int BK, int TM, int TN>
__launch_bounds__(256)
__global__ void gemm_nt(
    const float* __restrict__ A, const int* __restrict__ Aidx, int lda,
    const float* __restrict__ W, int ldw, int koff,
    const float* __restrict__ bias,
    const float* __restrict__ Dadd, int ldd, int dmask,
    float* __restrict__ C, int ldc,
    int M, int N, int K)
{
  constexpr int TX = BN / TN;
  constexpr int TY = BM / TM;
  static_assert(TX * TY == 256, "thread geometry");
  __shared__ float As[BK][BM + 4];   // k-major, +4 pad (row stride 16B-aligned)
  __shared__ float Ws[BK][BN + 4];

  const int tid = threadIdx.x;
  const int tx = tid % TX, ty = tid / TX;
  const int m0 = blockIdx.y * BM, n0 = blockIdx.x * BN;

  float acc[TM][TN];
#pragma unroll
  for (int i = 0; i < TM; ++i)
#pragma unroll
    for (int j = 0; j < TN; ++j) acc[i][j] = 0.f;

  constexpr int AV = (BM * BK) / 4;  // float4 elements in A tile
  constexpr int WV = (BN * BK) / 4;
  constexpr int KV = BK / 4;

  for (int k0 = 0; k0 < K; k0 += BK) {
#pragma unroll
    for (int l = 0; l < (AV + 255) / 256; ++l) {
      int e = tid + l * 256;
      if (e < AV) {
        int r = e / KV, kq = e % KV;
        int m = m0 + r;
        float4 v = make_float4(0.f, 0.f, 0.f, 0.f);
        if (m < M) {
          int row = Aidx ? Aidx[m] : m;
          v = *(const float4*)&A[(size_t)row * lda + k0 + kq * 4];
        }
        As[kq * 4 + 0][r] = v.x; As[kq * 4 + 1][r] = v.y;
        As[kq * 4 + 2][r] = v.z; As[kq * 4 + 3][r] = v.w;
      }
    }
#pragma unroll
    for (int l = 0; l < (WV + 255) / 256; ++l) {
      int e = tid + l * 256;
      if (e < WV) {
        int c = e / KV, kq = e % KV;
        int n = n0 + c;
        float4 v = make_float4(0.f, 0.f, 0.f, 0.f);
        if (n < N)
          v = *(const float4*)&W[(size_t)n * ldw + koff + k0 + kq * 4];
        Ws[kq * 4 + 0][c] = v.x; Ws[kq * 4 + 1][c] = v.y;
        Ws[kq * 4 + 2][c] = v.z; Ws[kq * 4 + 3][c] = v.w;
      }
    }
    __syncthreads();
#pragma unroll
    for (int kk = 0; kk < BK; ++kk) {
      float a[TM], b[TN];
      if constexpr (TM == 4) {
        float4 t = *(const float4*)&As[kk][ty * 4];
        a[0] = t.x; a[1] = t.y; a[2] = t.z; a[3] = t.w;
      } else {
#pragma unroll
        for (int i = 0; i < TM; ++i) a[i] = As[kk][ty * TM + i];
      }
      if constexpr (TN == 4) {
        float4 t = *(const float4*)&Ws[kk][tx * 4];
        b[0] = t.x; b[1] = t.y; b[2] = t.z; b[3] = t.w;
      } else {
#pragma unroll
        for (int j = 0; j < TN; ++j) b[j] = Ws[kk][tx * TN + j];
      }
#pragma unroll
      for (int i = 0; i < TM; ++i)
#pragma unroll
        for (int j = 0; j < TN; ++j)
          acc[i][j] += a[i] * b[j];
    }
    __syncthreads();
  }

#pragma unroll
  for (int i = 0; i < TM; ++i) {
    int m = m0 + ty * TM + i;
    if (m >= M) continue;
#pragma unroll
    for (int j = 0; j < TN; ++j) {
      int n = n0 + tx * TN + j;
      if (n >= N) continue;
      float v = acc[i][j];
      if (bias) v += bias[n];
      if (Dadd) {
        int dr = (dmask < 0) ? m : (m & dmask);
        v += Dadd[(size_t)dr * ldd + n];
      }
      C[(size_t)m * ldc + n] = v;
    }
  }
}

// gates[B,4H] (i,f,g,o) + c -> c', h'; optionally record h' into hs
__global__ void lstm_cell(const float* __restrict__ gates,
                          float* __restrict__ c, float* __restrict__ h,
                          float* __restrict__ hs) {
  int i = blockIdx.x * blockDim.x + threadIdx.x;  // 0 .. B*H-1
  int b = i >> 10, j = i & (H_ - 1);
  const float* g = gates + b * G_;
  float ig = g[j], fg = g[j + H_], gg = g[j + 2 * H_], og = g[j + 3 * H_];
  float si = 1.f / (1.f + __expf(-ig));
  float sf = 1.f / (1.f + __expf(-fg));
  float so = 1.f / (1.f + __expf(-og));
  float tg = tanhf(gg);
  float cn = sf * c[i] + si * tg;
  float hn = so * tanhf(cn);
  c[i] = cn;
  h[i] = hn;
  if (hs) hs[i] = hn;
}

extern "C" void kernel_launch(void* const* d_in, const int* in_sizes, int n_in,
                              void* d_out, int out_size, void* d_ws, size_t ws_size,
                              hipStream_t stream) {
  const int*   word  = (const int*)  d_in[0];
  const int*   seq   = (const int*)  d_in[1];
  const float* emb   = (const float*)d_in[2];
  const float* w2h_W = (const float*)d_in[3];
  const float* w2h_b = (const float*)d_in[4];
  const float* W_ih0 = (const float*)d_in[5];
  const float* W_hh0 = (const float*)d_in[6];
  const float* b_ih0 = (const float*)d_in[7];
  const float* b_hh0 = (const float*)d_in[8];
  const float* W_ih1 = (const float*)d_in[9];
  const float* W_hh1 = (const float*)d_in[10];
  const float* b_ih1 = (const float*)d_in[11];
  const float* b_hh1 = (const float*)d_in[12];
  const float* dec_W = (const float*)d_in[13];
  const float* dec_b = (const float*)d_in[14];

  float* out = (float*)d_out;
  // scratch inside the decoded region [0, 102,400,000) — clobber-safe layout:
  float* xg     = out;              // [T*B,4H]  = 13,107,200 fl, dead before decode
  float* hs0    = out + 97140736;   // [T*B,H]: hs0[t] dies before decode(t) reaches it
  float* gates  = out + 100417536;  // [B,4H], only decode t=49 clobbers (after last use)
  float* bias0c = out + 100679680;  // [4H]
  float* bias1c = out + 100683776;  // [4H]
  float* y_w    = out + 100687872;  // [B,4H], ends 100,950,016 < 102,400,000
  float* hL0 = out + 102400000;     // h_final[0] — doubles as live layer-0 h state
  float* hL1 = hL0 + B_ * H_;       // h_final[1]
  float* cL0 = out + 102531072;     // c_final[0] — live layer-0 c state
  float* cL1 = cL0 + B_ * H_;       // c_final[1]

  const bool useWs = ws_size >= (size_t)T_ * B_ * H_ * sizeof(float);
  float* hs1 = (float*)d_ws;

  // init: h0 = h1 = 0
  fill_zero<<<dim3((2 * B_ * H_ + 255) / 256), 256, 0, stream>>>(hL0, 2 * B_ * H_);
  // combined biases (b_ih + b_hh)
  vec_add<<<dim3(G_ / 256), 256, 0, stream>>>(bias0c, b_ih0, b_hh0, G_);
  vec_add<<<dim3(G_ / 256), 256, 0, stream>>>(bias1c, b_ih1, b_hh1, G_);

  // c0 = word_emb @ w2h_W^T + w2h_b  -> both layers' initial c
  gemm_nt<64, 64, 16, 4, 4><<<dim3(H_ / 64, 1), 256, 0, stream>>>(
      emb, word, E_, w2h_W, E_, 0, w2h_b, nullptr, 0, -1, cL0, H_, B_, H_, E_);
  gemm_nt<64, 64, 16, 4, 4><<<dim3(H_ / 64, 1), 256, 0, stream>>>(
      emb, word, E_, w2h_W, E_, 0, w2h_b, nullptr, 0, -1, cL1, H_, B_, H_, E_);

  // y_w = word_emb @ W_ih0[:, :E]^T + (b_ih0+b_hh0)   (time-invariant half)
  gemm_nt<64, 64, 16, 4, 4><<<dim3(G_ / 64, 1), 256, 0, stream>>>(
      emb, word, E_, W_ih0, 2 * E_, 0, bias0c, nullptr, 0, -1, y_w, G_, B_, G_, E_);

  // xg0 = seq_emb @ W_ih0[:, E:]^T + y_w[b]
  gemm_nt<64, 64, 16, 4, 4><<<dim3(G_ / 64, T_), 256, 0, stream>>>(
      emb, seq, E_, W_ih0, 2 * E_, E_, nullptr, y_w, G_, 63, xg, G_, T_ * B_, G_, E_);

  // ---- layer 0 recurrence ----
  for (int t = 0; t < T_; ++t) {
    gemm_nt<64, 8, 32, 2, 1><<<dim3(G_ / 8, 1), 256, 0, stream>>>(
        hL0, nullptr, H_, W_hh0, H_, 0, nullptr,
        xg + (size_t)t * B_ * G_, G_, -1, gates, G_, B_, G_, H_);
    lstm_cell<<<dim3(B_ * H_ / 256), 256, 0, stream>>>(
        gates, cL0, hL0, hs0 + (size_t)t * B_ * H_);
  }

  if (useWs) {
    // ---- path A: batched xg1 + batched decoder (hs1 in workspace) ----
    gemm_nt<64, 64, 16, 4, 4><<<dim3(G_ / 64, T_), 256, 0, stream>>>(
        hs0, nullptr, H_, W_ih1, H_, 0, bias1c, nullptr, 0, -1, xg, G_, T_ * B_, G_, H_);
    for (int t = 0; t < T_; ++t) {
      gemm_nt<64, 8, 32, 2, 1><<<dim3(G_ / 8, 1), 256, 0, stream>>>(
          hL1, nullptr, H_, W_hh1, H_, 0, nullptr,
          xg + (size_t)t * B_ * G_, G_, -1, gates, G_, B_, G_, H_);
      lstm_cell<<<dim3(B_ * H_ / 256), 256, 0, stream>>>(
          gates, cL1, hL1, hs1 + (size_t)t * B_ * H_);
    }
    gemm_nt<64, 64, 16, 4, 4><<<dim3(V_ / 64, T_), 256, 0, stream>>>(
        hs1, nullptr, H_, dec_W, H_, 0, dec_b, nullptr, 0, -1, out, V_, T_ * B_, V_, H_);
  } else {
    // ---- path B: per-timestep xg1 + per-timestep decode (zero ws) ----
    for (int t = 0; t < T_; ++t) {
      gemm_nt<64, 8, 32, 2, 1><<<dim3(G_ / 8, 1), 256, 0, stream>>>(
          hs0 + (size_t)t * B_ * H_, nullptr, H_, W_ih1, H_, 0, bias1c,
          nullptr, 0, -1, gates, G_, B_, G_, H_);
      gemm_nt<64, 8, 32, 2, 1><<<dim3(G_ / 8, 1), 256, 0, stream>>>(
          hL1, nullptr, H_, W_hh1, H_, 0, nullptr,
          gates, G_, -1, gates, G_, B_, G_, H_);
      lstm_cell<<<dim3(B_ * H_ / 256), 256, 0, stream>>>(gates, cL1, hL1, nullptr);
      gemm_nt<64, 64, 16, 4, 4><<<dim3(V_ / 64, 1), 256, 0, stream>>>(
          hL1, nullptr, H_, dec_W, H_, 0, dec_b, nullptr, 0, -1,
          out + (size_t)t * B_ * V_, V_, B_, V_, H_);
    }
  }
}

// Round 3
// 4215.509 us; speedup vs baseline: 2.2356x; 2.2356x over previous
//
#include <hip/hip_runtime.h>
#include <hip/hip_bf16.h>
#include <cstddef>

// ---------------------------------------------------------------------------
// RNNModel round 3 (= round 2 resubmit after infra failure):
// split-bf16 MFMA for big GEMMs + split-K fused recurrence.
// Gate columns use interleaved layout: output col n <-> source row perm_g(n),
//   perm_g(n) = ((n>>4)&3)*1024 + (n>>6)*16 + (n&15)
// so unit u's 4 gates live at cols (u>>4)*64 + g*16 + (u&15)  (cell-local).
// ---------------------------------------------------------------------------

static constexpr int T_ = 50, B_ = 64, E_ = 1024, H_ = 1024, V_ = 32000;
static constexpr int G_ = 4096;

typedef __attribute__((ext_vector_type(8))) short bf16x8;
typedef __attribute__((ext_vector_type(4))) float f32x4;

__device__ __forceinline__ int perm_g(int n) {
  return ((n >> 4) & 3) * H_ + (n >> 6) * 16 + (n & 15);
}

// split x into bf16 hi + bf16 lo (RNE), packed as 2x16-bit
__device__ __forceinline__ unsigned short bf16_rn(float x) {
  union { float f; unsigned u; } a; a.f = x;
  unsigned r = a.u + 0x7fffu + ((a.u >> 16) & 1u);
  return (unsigned short)(r >> 16);
}
__device__ __forceinline__ float bf16_f(unsigned short h) {
  union { float f; unsigned u; } a; a.u = ((unsigned)h) << 16;
  return a.f;
}
__device__ __forceinline__ void split4(float4 v, unsigned* hi2, unsigned* lo2) {
  unsigned short h0 = bf16_rn(v.x), h1 = bf16_rn(v.y),
                 h2 = bf16_rn(v.z), h3 = bf16_rn(v.w);
  unsigned short l0 = bf16_rn(v.x - bf16_f(h0)), l1 = bf16_rn(v.y - bf16_f(h1));
  unsigned short l2 = bf16_rn(v.z - bf16_f(h2)), l3 = bf16_rn(v.w - bf16_f(h3));
  hi2[0] = (unsigned)h0 | ((unsigned)h1 << 16);
  hi2[1] = (unsigned)h2 | ((unsigned)h3 << 16);
  lo2[0] = (unsigned)l0 | ((unsigned)l1 << 16);
  lo2[1] = (unsigned)l2 | ((unsigned)l3 << 16);
}

__global__ void fill_zero(float* p, int n) {
  int i = blockIdx.x * blockDim.x + threadIdx.x;
  if (i < n) p[i] = 0.f;
}
__global__ void vec_add(float* dst, const float* a, const float* b, int n) {
  int i = blockIdx.x * blockDim.x + threadIdx.x;
  if (i < n) dst[i] = a[i] + b[i];
}

// ------------------------- fp32 tiled GEMM (small uses) ---------------------
template<int BM, int BN, int BK, int TM, int TN>
__launch_bounds__(256)
__global__ void gemm_nt(
    const float* __restrict__ A, const int* __restrict__ Aidx, int lda,
    const float* __restrict__ W, int ldw, int koff,
    const float* __restrict__ bias,
    const float* __restrict__ Dadd, int ldd, int dmask,
    float* __restrict__ C, int ldc, int M, int N, int K)
{
  constexpr int TX = BN / TN;
  constexpr int TY = BM / TM;
  static_assert(TX * TY == 256, "thread geometry");
  __shared__ float As[BK][BM + 4];
  __shared__ float Ws[BK][BN + 4];
  const int tid = threadIdx.x;
  const int tx = tid % TX, ty = tid / TX;
  const int m0 = blockIdx.y * BM, n0 = blockIdx.x * BN;
  float acc[TM][TN];
#pragma unroll
  for (int i = 0; i < TM; ++i)
#pragma unroll
    for (int j = 0; j < TN; ++j) acc[i][j] = 0.f;
  constexpr int AV = (BM * BK) / 4;
  constexpr int WV = (BN * BK) / 4;
  constexpr int KV = BK / 4;
  for (int k0 = 0; k0 < K; k0 += BK) {
#pragma unroll
    for (int l = 0; l < (AV + 255) / 256; ++l) {
      int e = tid + l * 256;
      if (e < AV) {
        int r = e / KV, kq = e % KV;
        int m = m0 + r;
        float4 v = make_float4(0.f, 0.f, 0.f, 0.f);
        if (m < M) {
          int row = Aidx ? Aidx[m] : m;
          v = *(const float4*)&A[(size_t)row * lda + k0 + kq * 4];
        }
        As[kq * 4 + 0][r] = v.x; As[kq * 4 + 1][r] = v.y;
        As[kq * 4 + 2][r] = v.z; As[kq * 4 + 3][r] = v.w;
      }
    }
#pragma unroll
    for (int l = 0; l < (WV + 255) / 256; ++l) {
      int e = tid + l * 256;
      if (e < WV) {
        int c = e / KV, kq = e % KV;
        int n = n0 + c;
        float4 v = make_float4(0.f, 0.f, 0.f, 0.f);
        if (n < N)
          v = *(const float4*)&W[(size_t)n * ldw + koff + k0 + kq * 4];
        Ws[kq * 4 + 0][c] = v.x; Ws[kq * 4 + 1][c] = v.y;
        Ws[kq * 4 + 2][c] = v.z; Ws[kq * 4 + 3][c] = v.w;
      }
    }
    __syncthreads();
#pragma unroll
    for (int kk = 0; kk < BK; ++kk) {
      float a[TM], b[TN];
#pragma unroll
      for (int i = 0; i < TM; ++i) a[i] = As[kk][ty * TM + i];
#pragma unroll
      for (int j = 0; j < TN; ++j) b[j] = Ws[kk][tx * TN + j];
#pragma unroll
      for (int i = 0; i < TM; ++i)
#pragma unroll
        for (int j = 0; j < TN; ++j)
          acc[i][j] += a[i] * b[j];
    }
    __syncthreads();
  }
#pragma unroll
  for (int i = 0; i < TM; ++i) {
    int m = m0 + ty * TM + i;
    if (m >= M) continue;
#pragma unroll
    for (int j = 0; j < TN; ++j) {
      int n = n0 + tx * TN + j;
      if (n >= N) continue;
      float v = acc[i][j];
      if (bias) v += bias[n];
      if (Dadd) {
        int dr = (dmask < 0) ? m : (m & dmask);
        v += Dadd[(size_t)dr * ldd + n];
      }
      C[(size_t)m * ldc + n] = v;
    }
  }
}

// --------------------- split-bf16 MFMA GEMM (big GEMMs) ---------------------
// C[M,N] = A[M,K] @ W[N,K]^T (+bias) (+Dadd). 128x128 tile, BK=32, 4 waves.
template<bool GATHER, bool WPERM>
__launch_bounds__(256)
__global__ void gemm_sp(
    const float* __restrict__ A, const int* __restrict__ Aidx, int lda,
    const float* __restrict__ W, int ldw, int koff,
    const float* __restrict__ bias,
    const float* __restrict__ Dadd, int ldd, int dmask,
    float* __restrict__ C, int ldc, int M, int N, int K, int nbx)
{
  __shared__ unsigned short As_h[128][40], As_l[128][40];
  __shared__ unsigned short Ws_h[128][40], Ws_l[128][40];

  // bijective XCD swizzle (m204)
  int nwg = gridDim.x, bid = blockIdx.x;
  int q = nwg >> 3, r = nwg & 7;
  int xcd = bid & 7, base = bid >> 3;
  int wg = (xcd < r ? xcd * (q + 1) : r * (q + 1) + (xcd - r) * q) + base;
  int bx = wg % nbx, by = wg / nbx;
  const int m0 = by * 128, n0 = bx * 128;

  const int tid = threadIdx.x;
  const int wave = tid >> 6, lane = tid & 63;
  const int lr = lane & 15, lq = lane >> 4;
  const int wm = (wave >> 1) * 64, wn = (wave & 1) * 64;

  f32x4 acc[4][4] = {};

  for (int k0 = 0; k0 < K; k0 += 32) {
    // stage A tile (128x32 f32 -> hi/lo bf16)
#pragma unroll
    for (int l = 0; l < 4; ++l) {
      int s = tid + l * 256;          // 0..1023
      int row = s >> 3, kq = s & 7;
      float4 v = make_float4(0.f, 0.f, 0.f, 0.f);
      int gm = m0 + row;
      if (gm < M) {
        int src = GATHER ? Aidx[gm] : gm;
        v = *(const float4*)&A[(size_t)src * lda + k0 + kq * 4];
      }
      unsigned hi2[2], lo2[2];
      split4(v, hi2, lo2);
      *(uint2*)&As_h[row][kq * 4] = make_uint2(hi2[0], hi2[1]);
      *(uint2*)&As_l[row][kq * 4] = make_uint2(lo2[0], lo2[1]);
    }
    // stage W tile (128 rows x 32 k)
#pragma unroll
    for (int l = 0; l < 4; ++l) {
      int s = tid + l * 256;
      int col = s >> 3, kq = s & 7;
      int n = n0 + col;
      float4 v = make_float4(0.f, 0.f, 0.f, 0.f);
      if (n < N) {
        int srow = WPERM ? perm_g(n) : n;
        v = *(const float4*)&W[(size_t)srow * ldw + koff + k0 + kq * 4];
      }
      unsigned hi2[2], lo2[2];
      split4(v, hi2, lo2);
      *(uint2*)&Ws_h[col][kq * 4] = make_uint2(hi2[0], hi2[1]);
      *(uint2*)&Ws_l[col][kq * 4] = make_uint2(lo2[0], lo2[1]);
    }
    __syncthreads();

    bf16x8 ah[4], al[4], bh[4], bl[4];
#pragma unroll
    for (int i = 0; i < 4; ++i) {
      ah[i] = *(const bf16x8*)&As_h[wm + i * 16 + lr][lq * 8];
      al[i] = *(const bf16x8*)&As_l[wm + i * 16 + lr][lq * 8];
    }
#pragma unroll
    for (int j = 0; j < 4; ++j) {
      bh[j] = *(const bf16x8*)&Ws_h[wn + j * 16 + lr][lq * 8];
      bl[j] = *(const bf16x8*)&Ws_l[wn + j * 16 + lr][lq * 8];
    }
#pragma unroll
    for (int i = 0; i < 4; ++i)
#pragma unroll
      for (int j = 0; j < 4; ++j) {
        acc[i][j] = __builtin_amdgcn_mfma_f32_16x16x32_bf16(ah[i], bh[j], acc[i][j], 0, 0, 0);
        acc[i][j] = __builtin_amdgcn_mfma_f32_16x16x32_bf16(ah[i], bl[j], acc[i][j], 0, 0, 0);
        acc[i][j] = __builtin_amdgcn_mfma_f32_16x16x32_bf16(al[i], bh[j], acc[i][j], 0, 0, 0);
      }
    __syncthreads();
  }

  // epilogue: D row=(lane>>4)*4+reg, col=lane&15 (m89-verified)
#pragma unroll
  for (int i = 0; i < 4; ++i) {
    int mbase = m0 + wm + i * 16 + lq * 4;
#pragma unroll
    for (int j = 0; j < 4; ++j) {
      int n = n0 + wn + j * 16 + lr;
      if (n >= N) continue;
      float badd = bias ? bias[WPERM ? perm_g(n) : n] : 0.f;
#pragma unroll
      for (int rr = 0; rr < 4; ++rr) {
        int m = mbase + rr;
        if (m >= M) continue;
        float v = acc[i][j][rr] + badd;
        if (Dadd) {
          int dr = (dmask < 0) ? m : (m & dmask);
          v += Dadd[(size_t)dr * ldd + n];
        }
        C[(size_t)m * ldc + n] = v;
      }
    }
  }
}

// ------------------- recurrent step: split-K partial GEMM -------------------
// grid (64 n-tiles, 8 k-chunks); block 256. part[kc][64][4096] partial gates.
__launch_bounds__(256)
__global__ void rnn_part(const float* __restrict__ h, const float* __restrict__ Whh,
                         float* __restrict__ part)
{
  __shared__ float As[128][68];   // k-major: As[k][m], pad 4 (2-way conflicts only)
  __shared__ float Ws[128][68];   // k-major: Ws[k][c]
  const int n0 = blockIdx.x * 64, k0 = blockIdx.y * 128;
  const int tid = threadIdx.x;
#pragma unroll
  for (int l = 0; l < 8; ++l) {
    int s = tid + l * 256;        // 0..2047
    int m = s >> 5, kq = s & 31;
    float4 v = *(const float4*)&h[(size_t)m * H_ + k0 + kq * 4];
    As[kq * 4 + 0][m] = v.x; As[kq * 4 + 1][m] = v.y;
    As[kq * 4 + 2][m] = v.z; As[kq * 4 + 3][m] = v.w;
  }
#pragma unroll
  for (int l = 0; l < 8; ++l) {
    int s = tid + l * 256;
    int c = s >> 5, kq = s & 31;
    int srow = perm_g(n0 + c);
    float4 v = *(const float4*)&Whh[(size_t)srow * H_ + k0 + kq * 4];
    Ws[kq * 4 + 0][c] = v.x; Ws[kq * 4 + 1][c] = v.y;
    Ws[kq * 4 + 2][c] = v.z; Ws[kq * 4 + 3][c] = v.w;
  }
  __syncthreads();
  const int tx = tid & 15, ty = tid >> 4;
  float acc[4][4] = {};
  for (int kk = 0; kk < 128; ++kk) {
    float4 av = *(const float4*)&As[kk][ty * 4];
    float4 bv = *(const float4*)&Ws[kk][tx * 4];
    float a[4] = {av.x, av.y, av.z, av.w};
    float b[4] = {bv.x, bv.y, bv.z, bv.w};
#pragma unroll
    for (int i = 0; i < 4; ++i)
#pragma unroll
      for (int j = 0; j < 4; ++j) acc[i][j] += a[i] * b[j];
  }
  float* dst = part + (size_t)blockIdx.y * (B_ * G_);
#pragma unroll
  for (int i = 0; i < 4; ++i) {
    int m = ty * 4 + i;
    *(float4*)&dst[(size_t)m * G_ + n0 + tx * 4] =
        make_float4(acc[i][0], acc[i][1], acc[i][2], acc[i][3]);
  }
}

// reduce 8 partials + xg, apply LSTM cell. idx = m*1024 + u.
__global__ void rnn_cell(const float* __restrict__ part, const float* __restrict__ xg,
                         float* __restrict__ c, float* __restrict__ hstate,
                         float* __restrict__ hs)
{
  int idx = blockIdx.x * 256 + threadIdx.x;    // 0..65535
  int m = idx >> 10, u = idx & 1023;
  int cb = ((u >> 4) << 6) + (u & 15);
  float g4[4];
#pragma unroll
  for (int g = 0; g < 4; ++g) {
    int col = cb + (g << 4);
    size_t off = (size_t)m * G_ + col;
    float s = xg[off];
#pragma unroll
    for (int p = 0; p < 8; ++p) s += part[(size_t)p * (B_ * G_) + off];
    g4[g] = s;
  }
  float si = 1.f / (1.f + __expf(-g4[0]));
  float sf = 1.f / (1.f + __expf(-g4[1]));
  float tg = tanhf(g4[2]);
  float so = 1.f / (1.f + __expf(-g4[3]));
  float cn = sf * c[idx] + si * tg;
  float hn = so * tanhf(cn);
  c[idx] = cn;
  hstate[idx] = hn;
  if (hs) hs[idx] = hn;
}

// ---------------------------------------------------------------------------
extern "C" void kernel_launch(void* const* d_in, const int* in_sizes, int n_in,
                              void* d_out, int out_size, void* d_ws, size_t ws_size,
                              hipStream_t stream) {
  const int*   word  = (const int*)  d_in[0];
  const int*   seq   = (const int*)  d_in[1];
  const float* emb   = (const float*)d_in[2];
  const float* w2h_W = (const float*)d_in[3];
  const float* w2h_b = (const float*)d_in[4];
  const float* W_ih0 = (const float*)d_in[5];
  const float* W_hh0 = (const float*)d_in[6];
  const float* b_ih0 = (const float*)d_in[7];
  const float* b_hh0 = (const float*)d_in[8];
  const float* W_ih1 = (const float*)d_in[9];
  const float* W_hh1 = (const float*)d_in[10];
  const float* b_ih1 = (const float*)d_in[11];
  const float* b_hh1 = (const float*)d_in[12];
  const float* dec_W = (const float*)d_in[13];
  const float* dec_b = (const float*)d_in[14];

  float* out = (float*)d_out;
  // clobber-safe scratch inside the decoded region [0, 102,400,000):
  float* xg0    = out;               // [3200,4096], dead before layer-1
  float* part   = out + 14000000;    // [8][64][4096] = 2,097,152 fl, per-step life
  float* hs0    = out + 20000000;    // [3200,1024], dead after xg1 GEMM
  float* xg1    = out + 87560192;    // [3200,4096]: xg1[t] dies before decode(t-1) hits it
  float* bias0c = out + 100700000;   // [4096]
  float* bias1c = out + 100704096;   // [4096]
  float* y_w    = out + 100708192;   // [64,4096], dead after xg0 GEMM
  float* hL0 = out + 102400000;      // h_final[0] (live layer-0 h)
  float* hL1 = hL0 + B_ * H_;        // h_final[1]
  float* cL0 = out + 102531072;      // c_final[0]
  float* cL1 = cL0 + B_ * H_;

  const bool useWs = ws_size >= (size_t)T_ * B_ * H_ * sizeof(float);
  float* hs1 = (float*)d_ws;

  fill_zero<<<512, 256, 0, stream>>>(hL0, 2 * B_ * H_);
  vec_add<<<16, 256, 0, stream>>>(bias0c, b_ih0, b_hh0, G_);
  vec_add<<<16, 256, 0, stream>>>(bias1c, b_ih1, b_hh1, G_);

  // c0 = word_emb @ w2h_W^T + w2h_b (both layers)
  gemm_nt<64, 64, 16, 4, 4><<<dim3(16, 1), 256, 0, stream>>>(
      emb, word, E_, w2h_W, E_, 0, w2h_b, nullptr, 0, -1, cL0, H_, B_, H_, E_);
  gemm_nt<64, 64, 16, 4, 4><<<dim3(16, 1), 256, 0, stream>>>(
      emb, word, E_, w2h_W, E_, 0, w2h_b, nullptr, 0, -1, cL1, H_, B_, H_, E_);

  // y_w = word_emb @ W_ih0[:, :E]^T + (b_ih0+b_hh0)   (permuted cols)
  gemm_sp<true, true><<<32, 256, 0, stream>>>(
      emb, word, E_, W_ih0, 2 * E_, 0, bias0c, nullptr, 0, -1,
      y_w, G_, B_, G_, E_, 32);
  // xg0 = seq_emb @ W_ih0[:, E:]^T + y_w[b]           (permuted cols)
  gemm_sp<true, true><<<800, 256, 0, stream>>>(
      emb, seq, E_, W_ih0, 2 * E_, E_, nullptr, y_w, G_, 63,
      xg0, G_, T_ * B_, G_, E_, 32);

  // ---- layer 0 recurrence ----
  for (int t = 0; t < T_; ++t) {
    rnn_part<<<dim3(64, 8), 256, 0, stream>>>(hL0, W_hh0, part);
    rnn_cell<<<256, 256, 0, stream>>>(part, xg0 + (size_t)t * B_ * G_,
                                      cL0, hL0, hs0 + (size_t)t * B_ * H_);
  }

  // xg1 = hs0 @ W_ih1^T + (b_ih1+b_hh1)               (permuted cols)
  gemm_sp<false, true><<<800, 256, 0, stream>>>(
      hs0, nullptr, H_, W_ih1, H_, 0, bias1c, nullptr, 0, -1,
      xg1, G_, T_ * B_, G_, H_, 32);

  // ---- layer 1 recurrence (+ inline decode fallback) ----
  for (int t = 0; t < T_; ++t) {
    rnn_part<<<dim3(64, 8), 256, 0, stream>>>(hL1, W_hh1, part);
    rnn_cell<<<256, 256, 0, stream>>>(part, xg1 + (size_t)t * B_ * G_,
                                      cL1, hL1,
                                      useWs ? hs1 + (size_t)t * B_ * H_ : nullptr);
    if (!useWs) {
      gemm_sp<false, false><<<250, 256, 0, stream>>>(
          hL1, nullptr, H_, dec_W, H_, 0, dec_b, nullptr, 0, -1,
          out + (size_t)t * B_ * V_, V_, B_, V_, H_, 250);
    }
  }

  // batched decoder
  if (useWs) {
    gemm_sp<false, false><<<6250, 256, 0, stream>>>(
        hs1, nullptr, H_, dec_W, H_, 0, dec_b, nullptr, 0, -1,
        out, V_, T_ * B_, V_, H_, 250);
  }
}

// Round 4
// 2997.021 us; speedup vs baseline: 3.1445x; 1.4066x over previous
//
#include <hip/hip_runtime.h>
#include <cstddef>

// ---------------------------------------------------------------------------
// RNNModel round 4: all big GEMMs as single pure-bf16 (hi|lo, K=2048) MFMA
// GEMMs with chunk-XOR-permuted operands (swizzle baked into producers so
// global_load_lds stays linear); fused 1-launch-per-step recurrence.
// Gate permutation: output col n <-> W row perm_g(n)=((n>>4)&3)*1024+(n>>6)*16+(n&15)
// Chunk permute: within each 128B row-segment, 16B chunk c stored at c^(row&7).
// ---------------------------------------------------------------------------

static constexpr int T_ = 50, B_ = 64, E_ = 1024, H_ = 1024, V_ = 32000;
static constexpr int G_ = 4096;

typedef unsigned short u16;
typedef __attribute__((ext_vector_type(8))) short bf16x8;
typedef __attribute__((ext_vector_type(8))) unsigned short u16x8;
typedef __attribute__((ext_vector_type(4))) float f32x4;

__device__ __forceinline__ int perm_g(int n) {
  return ((n >> 4) & 3) * H_ + (n >> 6) * 16 + (n & 15);
}
__device__ __forceinline__ u16 bf16_rn(float x) {
  union { float f; unsigned u; } a; a.f = x;
  unsigned r = a.u + 0x7fffu + ((a.u >> 16) & 1u);
  return (u16)(r >> 16);
}
__device__ __forceinline__ float bf16_f(u16 h) {
  union { float f; unsigned u; } a; a.u = ((unsigned)h) << 16;
  return a.f;
}
__device__ __forceinline__ float sigm(float x) { return 1.f / (1.f + __expf(-x)); }

__global__ void fill_zero(float* p, int n) {
  int i = blockIdx.x * blockDim.x + threadIdx.x;
  if (i < n) p[i] = 0.f;
}
__global__ void vec_add(float* dst, const float* a, const float* b, int n) {
  int i = blockIdx.x * blockDim.x + threadIdx.x;
  if (i < n) dst[i] = a[i] + b[i];
}
// permuted combined bias: dst[n] = a[perm_g(n)] + b[perm_g(n)]
__global__ void bias_perm(const float* a, const float* b, float* dst) {
  int n = blockIdx.x * 256 + threadIdx.x;
  int s = perm_g(n);
  dst[n] = a[s] + b[s];
}

// f32 [rows x >=coloff+1024] -> bf16 hi|lo [rows x 2048] with chunk permute.
// source row: gidx ? gidx[r] : (PERM ? perm_g(r) : r)
__global__ void conv_w(const float* __restrict__ src, int srcld, int coloff,
                       const int* __restrict__ gidx, int PERM, int rows,
                       u16* __restrict__ dst) {
  int idx = blockIdx.x * 256 + threadIdx.x;
  int r = idx >> 7, kc = (idx & 127) << 3;
  if (r >= rows) return;
  int s = gidx ? gidx[r] : (PERM ? perm_g(r) : r);
  const float* p = src + (size_t)s * srcld + coloff + kc;
  float4 v0 = *(const float4*)p, v1 = *(const float4*)(p + 4);
  float vv[8] = {v0.x, v0.y, v0.z, v0.w, v1.x, v1.y, v1.z, v1.w};
  u16x8 hi, lo;
#pragma unroll
  for (int i = 0; i < 8; ++i) {
    u16 h = bf16_rn(vv[i]);
    hi[i] = h;
    lo[i] = bf16_rn(vv[i] - bf16_f(h));
  }
  size_t o = (size_t)r * 2048 + ((kc >> 6) << 6) + ((((kc >> 3) & 7) ^ (r & 7)) << 3);
  *(u16x8*)&dst[o] = hi;
  *(u16x8*)&dst[o + 1024] = lo;
}

// ----------------- pure-bf16 MFMA GEMM: C = A @ Wb^T (+bias)(+Dadd) --------
// A [M][2048] u16 chunk-permuted, Wb [N][2048] u16 chunk-permuted.
// 128x128 tile, BK=64, 4 waves, global_load_lds(16B) staging, XCD swizzle.
__launch_bounds__(256)
__global__ void gemm_bt(const u16* __restrict__ A, int Mrows,
                        const u16* __restrict__ Wb,
                        const float* __restrict__ bias,
                        const float* __restrict__ Dadd, int ldd, int dmask,
                        float* __restrict__ C, int ldc, int N, int nbx) {
  __shared__ u16 lsA[128 * 64];   // [row][64] = 128B/row, 16KB
  __shared__ u16 lsB[128 * 64];

  int nwg = gridDim.x, bid = blockIdx.x;
  int q = nwg >> 3, r = nwg & 7;
  int xcd = bid & 7, base = bid >> 3;
  int wg = (xcd < r ? xcd * (q + 1) : r * (q + 1) + (xcd - r) * q) + base;
  int bx = wg % nbx, by = wg / nbx;
  const int m0 = by * 128, n0 = bx * 128;

  const int tid = threadIdx.x, w = tid >> 6, l = tid & 63;
  const int lr = l & 15, lq = l >> 4;
  const int wm = (w >> 1) * 64, wn = (w & 1) * 64;

  f32x4 acc[4][4] = {};

  for (int kt = 0; kt < 32; ++kt) {
#pragma unroll
    for (int i = 0; i < 4; ++i) {
      int rb = w * 32 + i * 8;
      int gm = m0 + rb + (l >> 3);
      if (gm > Mrows - 1) gm = Mrows - 1;
      const u16* ga = A + (size_t)gm * 2048 + kt * 64 + (l & 7) * 8;
      __builtin_amdgcn_global_load_lds(
          (const __attribute__((address_space(1))) void*)ga,
          (__attribute__((address_space(3))) void*)(lsA + rb * 64), 16, 0, 0);
      const u16* gb = Wb + (size_t)(n0 + rb + (l >> 3)) * 2048 + kt * 64 + (l & 7) * 8;
      __builtin_amdgcn_global_load_lds(
          (const __attribute__((address_space(1))) void*)gb,
          (__attribute__((address_space(3))) void*)(lsB + rb * 64), 16, 0, 0);
    }
    asm volatile("s_waitcnt vmcnt(0)" ::: "memory");
    __syncthreads();

    bf16x8 af[4][2], bfr[4][2];
#pragma unroll
    for (int i = 0; i < 4; ++i) {
      int ar = wm + i * 16 + lr;
#pragma unroll
      for (int s = 0; s < 2; ++s)
        af[i][s] = *(const bf16x8*)&lsA[ar * 64 + (((s << 2) + lq) ^ (ar & 7)) * 8];
    }
#pragma unroll
    for (int j = 0; j < 4; ++j) {
      int br = wn + j * 16 + lr;
#pragma unroll
      for (int s = 0; s < 2; ++s)
        bfr[j][s] = *(const bf16x8*)&lsB[br * 64 + (((s << 2) + lq) ^ (br & 7)) * 8];
    }
#pragma unroll
    for (int i = 0; i < 4; ++i)
#pragma unroll
      for (int j = 0; j < 4; ++j) {
        acc[i][j] = __builtin_amdgcn_mfma_f32_16x16x32_bf16(af[i][0], bfr[j][0], acc[i][j], 0, 0, 0);
        acc[i][j] = __builtin_amdgcn_mfma_f32_16x16x32_bf16(af[i][1], bfr[j][1], acc[i][j], 0, 0, 0);
      }
    __syncthreads();
  }

#pragma unroll
  for (int i = 0; i < 4; ++i) {
    int mbase = m0 + wm + i * 16 + lq * 4;
#pragma unroll
    for (int j = 0; j < 4; ++j) {
      int n = n0 + wn + j * 16 + lr;
      float badd = bias ? bias[n] : 0.f;
#pragma unroll
      for (int rr = 0; rr < 4; ++rr) {
        int m = mbase + rr;
        if (m >= Mrows) continue;
        float v = acc[i][j][rr] + badd;
        if (Dadd) {
          int dr = (dmask < 0) ? m : (m & dmask);
          v += Dadd[(size_t)dr * ldd + n];
        }
        C[(size_t)m * ldc + n] = v;
      }
    }
  }
}

// --------------- fused recurrent step: gates GEMM + LSTM cell --------------
// grid 64 (n-tiles of 64 perm'd cols = 16 units), block 256 (4 waves x 16 rows).
// hprev [64][2048] u16 permuted; Wb [4096][2048] u16; xg [64][4096] f32.
template<bool EMIT_F32>
__launch_bounds__(256)
__global__ void rnn_step(const u16* __restrict__ hprev, const u16* __restrict__ Wb,
                         const float* __restrict__ xg,
                         float* __restrict__ c, float* __restrict__ hf,
                         u16* __restrict__ hbf_out, float* __restrict__ hsf) {
  __shared__ char smem[32768];
  u16* lsA = (u16*)smem;                 // [64][128] = 256B/row, 16KB
  u16* lsB = (u16*)(smem + 16384);

  const int nt = blockIdx.x, n0 = nt * 64;
  const int tid = threadIdx.x, w = tid >> 6, l = tid & 63;
  const int lr = l & 15, lq = l >> 4;

  f32x4 acc[4] = {};

  for (int kt = 0; kt < 16; ++kt) {
#pragma unroll
    for (int i = 0; i < 4; ++i) {
      int rb = w * 16 + i * 4;
      const u16* ga = hprev + (size_t)(rb + (l >> 4)) * 2048 + kt * 128 + (l & 15) * 8;
      __builtin_amdgcn_global_load_lds(
          (const __attribute__((address_space(1))) void*)ga,
          (__attribute__((address_space(3))) void*)(lsA + rb * 128), 16, 0, 0);
      const u16* gb = Wb + (size_t)(n0 + rb + (l >> 4)) * 2048 + kt * 128 + (l & 15) * 8;
      __builtin_amdgcn_global_load_lds(
          (const __attribute__((address_space(1))) void*)gb,
          (__attribute__((address_space(3))) void*)(lsB + rb * 128), 16, 0, 0);
    }
    asm volatile("s_waitcnt vmcnt(0)" ::: "memory");
    __syncthreads();

    bf16x8 af[4];
    int ar = w * 16 + lr;
#pragma unroll
    for (int s = 0; s < 4; ++s)
      af[s] = *(const bf16x8*)&lsA[ar * 128 + (s >> 1) * 64 + ((((s & 1) << 2) + lq) ^ (ar & 7)) * 8];
#pragma unroll
    for (int j = 0; j < 4; ++j) {
      int br = j * 16 + lr;
#pragma unroll
      for (int s = 0; s < 4; ++s) {
        bf16x8 bv = *(const bf16x8*)&lsB[br * 128 + (s >> 1) * 64 + ((((s & 1) << 2) + lq) ^ (br & 7)) * 8];
        acc[j] = __builtin_amdgcn_mfma_f32_16x16x32_bf16(af[s], bv, acc[j], 0, 0, 0);
      }
    }
    __syncthreads();
  }

  // gates -> LDS (reuse smem), then cell
  float* gsh = (float*)smem;   // [64][68]
#pragma unroll
  for (int j = 0; j < 4; ++j)
#pragma unroll
    for (int rr = 0; rr < 4; ++rr)
      gsh[(w * 16 + lq * 4 + rr) * 68 + j * 16 + lr] = acc[j][rr];
  __syncthreads();

  const int u16i = tid & 15, mq = tid >> 4;
#pragma unroll
  for (int mr = 0; mr < 4; ++mr) {
    int m = mr * 16 + mq;
    float gi = gsh[m * 68 + 0 + u16i]  + xg[(size_t)m * G_ + n0 + 0 + u16i];
    float gf = gsh[m * 68 + 16 + u16i] + xg[(size_t)m * G_ + n0 + 16 + u16i];
    float gg = gsh[m * 68 + 32 + u16i] + xg[(size_t)m * G_ + n0 + 32 + u16i];
    float go = gsh[m * 68 + 48 + u16i] + xg[(size_t)m * G_ + n0 + 48 + u16i];
    int unit = nt * 16 + u16i;
    int ci = m * H_ + unit;
    float cn = sigm(gf) * c[ci] + sigm(gi) * tanhf(gg);
    float hn = sigm(go) * tanhf(cn);
    c[ci] = cn;
    hf[ci] = hn;
    if (EMIT_F32) hsf[ci] = hn;
    u16 hh = bf16_rn(hn);
    u16 hl = bf16_rn(hn - bf16_f(hh));
    // permuted bf16 store: hi at k=unit, lo at k=1024+unit
    size_t oh = (size_t)m * 2048 + ((unit >> 6) << 6) +
                ((((unit >> 3) & 7) ^ (m & 7)) << 3) + (unit & 7);
    hbf_out[oh] = hh;
    hbf_out[oh + 1024] = hl;
  }
}

// ======================= legacy kernels (tier 2/3 paths) ====================
template<int BM, int BN, int BK, int TM, int TN>
__launch_bounds__(256)
__global__ void gemm_nt(
    const float* __restrict__ A, const int* __restrict__ Aidx, int lda,
    const float* __restrict__ W, int ldw, int koff,
    const float* __restrict__ bias,
    const float* __restrict__ Dadd, int ldd, int dmask,
    float* __restrict__ C, int ldc, int M, int N, int K) {
  constexpr int TX = BN / TN;
  constexpr int TY = BM / TM;
  static_assert(TX * TY == 256, "thread geometry");
  __shared__ float As[BK][BM + 4];
  __shared__ float Ws[BK][BN + 4];
  const int tid = threadIdx.x;
  const int tx = tid % TX, ty = tid / TX;
  const int m0 = blockIdx.y * BM, n0 = blockIdx.x * BN;
  float acc[TM][TN];
#pragma unroll
  for (int i = 0; i < TM; ++i)
#pragma unroll
    for (int j = 0; j < TN; ++j) acc[i][j] = 0.f;
  constexpr int AV = (BM * BK) / 4;
  constexpr int WV = (BN * BK) / 4;
  constexpr int KV = BK / 4;
  for (int k0 = 0; k0 < K; k0 += BK) {
#pragma unroll
    for (int lp = 0; lp < (AV + 255) / 256; ++lp) {
      int e = tid + lp * 256;
      if (e < AV) {
        int r = e / KV, kq = e % KV;
        int m = m0 + r;
        float4 v = make_float4(0.f, 0.f, 0.f, 0.f);
        if (m < M) {
          int row = Aidx ? Aidx[m] : m;
          v = *(const float4*)&A[(size_t)row * lda + k0 + kq * 4];
        }
        As[kq * 4 + 0][r] = v.x; As[kq * 4 + 1][r] = v.y;
        As[kq * 4 + 2][r] = v.z; As[kq * 4 + 3][r] = v.w;
      }
    }
#pragma unroll
    for (int lp = 0; lp < (WV + 255) / 256; ++lp) {
      int e = tid + lp * 256;
      if (e < WV) {
        int cc = e / KV, kq = e % KV;
        int n = n0 + cc;
        float4 v = make_float4(0.f, 0.f, 0.f, 0.f);
        if (n < N)
          v = *(const float4*)&W[(size_t)n * ldw + koff + k0 + kq * 4];
        Ws[kq * 4 + 0][cc] = v.x; Ws[kq * 4 + 1][cc] = v.y;
        Ws[kq * 4 + 2][cc] = v.z; Ws[kq * 4 + 3][cc] = v.w;
      }
    }
    __syncthreads();
#pragma unroll
    for (int kk = 0; kk < BK; ++kk) {
      float a[TM], b[TN];
#pragma unroll
      for (int i = 0; i < TM; ++i) a[i] = As[kk][ty * TM + i];
#pragma unroll
      for (int j = 0; j < TN; ++j) b[j] = Ws[kk][tx * TN + j];
#pragma unroll
      for (int i = 0; i < TM; ++i)
#pragma unroll
        for (int j = 0; j < TN; ++j)
          acc[i][j] += a[i] * b[j];
    }
    __syncthreads();
  }
#pragma unroll
  for (int i = 0; i < TM; ++i) {
    int m = m0 + ty * TM + i;
    if (m >= M) continue;
#pragma unroll
    for (int j = 0; j < TN; ++j) {
      int n = n0 + tx * TN + j;
      if (n >= N) continue;
      float v = acc[i][j];
      if (bias) v += bias[n];
      if (Dadd) {
        int dr = (dmask < 0) ? m : (m & dmask);
        v += Dadd[(size_t)dr * ldd + n];
      }
      C[(size_t)m * ldc + n] = v;
    }
  }
}

__device__ __forceinline__ void split4(float4 v, unsigned* hi2, unsigned* lo2) {
  u16 h0 = bf16_rn(v.x), h1 = bf16_rn(v.y), h2 = bf16_rn(v.z), h3 = bf16_rn(v.w);
  u16 l0 = bf16_rn(v.x - bf16_f(h0)), l1 = bf16_rn(v.y - bf16_f(h1));
  u16 l2 = bf16_rn(v.z - bf16_f(h2)), l3 = bf16_rn(v.w - bf16_f(h3));
  hi2[0] = (unsigned)h0 | ((unsigned)h1 << 16);
  hi2[1] = (unsigned)h2 | ((unsigned)h3 << 16);
  lo2[0] = (unsigned)l0 | ((unsigned)l1 << 16);
  lo2[1] = (unsigned)l2 | ((unsigned)l3 << 16);
}

template<bool GATHER, bool WPERM>
__launch_bounds__(256)
__global__ void gemm_sp(
    const float* __restrict__ A, const int* __restrict__ Aidx, int lda,
    const float* __restrict__ W, int ldw, int koff,
    const float* __restrict__ bias,
    const float* __restrict__ Dadd, int ldd, int dmask,
    float* __restrict__ C, int ldc, int M, int N, int K, int nbx) {
  __shared__ u16 As_h[128][40], As_l[128][40];
  __shared__ u16 Ws_h[128][40], Ws_l[128][40];
  int nwg = gridDim.x, bid = blockIdx.x;
  int q = nwg >> 3, r = nwg & 7;
  int xcd = bid & 7, base = bid >> 3;
  int wg = (xcd < r ? xcd * (q + 1) : r * (q + 1) + (xcd - r) * q) + base;
  int bx = wg % nbx, by = wg / nbx;
  const int m0 = by * 128, n0 = bx * 128;
  const int tid = threadIdx.x;
  const int wave = tid >> 6, lane = tid & 63;
  const int lr = lane & 15, lq = lane >> 4;
  const int wm = (wave >> 1) * 64, wn = (wave & 1) * 64;
  f32x4 acc[4][4] = {};
  for (int k0 = 0; k0 < K; k0 += 32) {
#pragma unroll
    for (int lp = 0; lp < 4; ++lp) {
      int s = tid + lp * 256;
      int row = s >> 3, kq = s & 7;
      float4 v = make_float4(0.f, 0.f, 0.f, 0.f);
      int gm = m0 + row;
      if (gm < M) {
        int src = GATHER ? Aidx[gm] : gm;
        v = *(const float4*)&A[(size_t)src * lda + k0 + kq * 4];
      }
      unsigned hi2[2], lo2[2];
      split4(v, hi2, lo2);
      *(uint2*)&As_h[row][kq * 4] = make_uint2(hi2[0], hi2[1]);
      *(uint2*)&As_l[row][kq * 4] = make_uint2(lo2[0], lo2[1]);
    }
#pragma unroll
    for (int lp = 0; lp < 4; ++lp) {
      int s = tid + lp * 256;
      int col = s >> 3, kq = s & 7;
      int n = n0 + col;
      float4 v = make_float4(0.f, 0.f, 0.f, 0.f);
      if (n < N) {
        int srow = WPERM ? perm_g(n) : n;
        v = *(const float4*)&W[(size_t)srow * ldw + koff + k0 + kq * 4];
      }
      unsigned hi2[2], lo2[2];
      split4(v, hi2, lo2);
      *(uint2*)&Ws_h[col][kq * 4] = make_uint2(hi2[0], hi2[1]);
      *(uint2*)&Ws_l[col][kq * 4] = make_uint2(lo2[0], lo2[1]);
    }
    __syncthreads();
    bf16x8 ah[4], al[4], bh[4], bl[4];
#pragma unroll
    for (int i = 0; i < 4; ++i) {
      ah[i] = *(const bf16x8*)&As_h[wm + i * 16 + lr][lq * 8];
      al[i] = *(const bf16x8*)&As_l[wm + i * 16 + lr][lq * 8];
    }
#pragma unroll
    for (int j = 0; j < 4; ++j) {
      bh[j] = *(const bf16x8*)&Ws_h[wn + j * 16 + lr][lq * 8];
      bl[j] = *(const bf16x8*)&Ws_l[wn + j * 16 + lr][lq * 8];
    }
#pragma unroll
    for (int i = 0; i < 4; ++i)
#pragma unroll
      for (int j = 0; j < 4; ++j) {
        acc[i][j] = __builtin_amdgcn_mfma_f32_16x16x32_bf16(ah[i], bh[j], acc[i][j], 0, 0, 0);
        acc[i][j] = __builtin_amdgcn_mfma_f32_16x16x32_bf16(ah[i], bl[j], acc[i][j], 0, 0, 0);
        acc[i][j] = __builtin_amdgcn_mfma_f32_16x16x32_bf16(al[i], bh[j], acc[i][j], 0, 0, 0);
      }
    __syncthreads();
  }
#pragma unroll
  for (int i = 0; i < 4; ++i) {
    int mbase = m0 + wm + i * 16 + lq * 4;
#pragma unroll
    for (int j = 0; j < 4; ++j) {
      int n = n0 + wn + j * 16 + lr;
      if (n >= N) continue;
      float badd = bias ? bias[WPERM ? perm_g(n) : n] : 0.f;
#pragma unroll
      for (int rr = 0; rr < 4; ++rr) {
        int m = mbase + rr;
        if (m >= M) continue;
        float v = acc[i][j][rr] + badd;
        if (Dadd) {
          int dr = (dmask < 0) ? m : (m & dmask);
          v += Dadd[(size_t)dr * ldd + n];
        }
        C[(size_t)m * ldc + n] = v;
      }
    }
  }
}

__launch_bounds__(256)
__global__ void rnn_part(const float* __restrict__ h, const float* __restrict__ Whh,
                         float* __restrict__ part) {
  __shared__ float As[128][68];
  __shared__ float Ws[128][68];
  const int n0 = blockIdx.x * 64, k0 = blockIdx.y * 128;
  const int tid = threadIdx.x;
#pragma unroll
  for (int lp = 0; lp < 8; ++lp) {
    int s = tid + lp * 256;
    int m = s >> 5, kq = s & 31;
    float4 v = *(const float4*)&h[(size_t)m * H_ + k0 + kq * 4];
    As[kq * 4 + 0][m] = v.x; As[kq * 4 + 1][m] = v.y;
    As[kq * 4 + 2][m] = v.z; As[kq * 4 + 3][m] = v.w;
  }
#pragma unroll
  for (int lp = 0; lp < 8; ++lp) {
    int s = tid + lp * 256;
    int cc = s >> 5, kq = s & 31;
    int srow = perm_g(n0 + cc);
    float4 v = *(const float4*)&Whh[(size_t)srow * H_ + k0 + kq * 4];
    Ws[kq * 4 + 0][cc] = v.x; Ws[kq * 4 + 1][cc] = v.y;
    Ws[kq * 4 + 2][cc] = v.z; Ws[kq * 4 + 3][cc] = v.w;
  }
  __syncthreads();
  const int tx = tid & 15, ty = tid >> 4;
  float acc[4][4] = {};
  for (int kk = 0; kk < 128; ++kk) {
    float4 av = *(const float4*)&As[kk][ty * 4];
    float4 bv = *(const float4*)&Ws[kk][tx * 4];
    float a[4] = {av.x, av.y, av.z, av.w};
    float b[4] = {bv.x, bv.y, bv.z, bv.w};
#pragma unroll
    for (int i = 0; i < 4; ++i)
#pragma unroll
      for (int j = 0; j < 4; ++j) acc[i][j] += a[i] * b[j];
  }
  float* dst = part + (size_t)blockIdx.y * (B_ * G_);
#pragma unroll
  for (int i = 0; i < 4; ++i) {
    int m = ty * 4 + i;
    *(float4*)&dst[(size_t)m * G_ + n0 + tx * 4] =
        make_float4(acc[i][0], acc[i][1], acc[i][2], acc[i][3]);
  }
}

__global__ void rnn_cell(const float* __restrict__ part, const float* __restrict__ xg,
                         float* __restrict__ c, float* __restrict__ hstate,
                         float* __restrict__ hs) {
  int idx = blockIdx.x * 256 + threadIdx.x;
  int m = idx >> 10, u = idx & 1023;
  int cb = ((u >> 4) << 6) + (u & 15);
  float g4[4];
#pragma unroll
  for (int g = 0; g < 4; ++g) {
    int col = cb + (g << 4);
    size_t off = (size_t)m * G_ + col;
    float s = xg[off];
#pragma unroll
    for (int p = 0; p < 8; ++p) s += part[(size_t)p * (B_ * G_) + off];
    g4[g] = s;
  }
  float cn = sigm(g4[1]) * c[idx] + sigm(g4[0]) * tanhf(g4[2]);
  float hn = sigm(g4[3]) * tanhf(cn);
  c[idx] = cn;
  hstate[idx] = hn;
  if (hs) hs[idx] = hn;
}

// ---------------------------------------------------------------------------
extern "C" void kernel_launch(void* const* d_in, const int* in_sizes, int n_in,
                              void* d_out, int out_size, void* d_ws, size_t ws_size,
                              hipStream_t stream) {
  const int*   word  = (const int*)  d_in[0];
  const int*   seq   = (const int*)  d_in[1];
  const float* emb   = (const float*)d_in[2];
  const float* w2h_W = (const float*)d_in[3];
  const float* w2h_b = (const float*)d_in[4];
  const float* W_ih0 = (const float*)d_in[5];
  const float* W_hh0 = (const float*)d_in[6];
  const float* b_ih0 = (const float*)d_in[7];
  const float* b_hh0 = (const float*)d_in[8];
  const float* W_ih1 = (const float*)d_in[9];
  const float* W_hh1 = (const float*)d_in[10];
  const float* b_ih1 = (const float*)d_in[11];
  const float* b_hh1 = (const float*)d_in[12];
  const float* dec_W = (const float*)d_in[13];
  const float* dec_b = (const float*)d_in[14];

  float* out = (float*)d_out;
  // state (beyond decoded region [0, 102,400,000)) — part of output
  float* hL0 = out + 102400000;
  float* hL1 = hL0 + B_ * H_;
  float* cL0 = out + 102531072;
  float* cL1 = cL0 + B_ * H_;

  const size_t need_hs1  = (size_t)T_ * B_ * H_ * 4;                 // 13,107,200 B
  const size_t need_full = need_hs1 + (size_t)V_ * 2048 * 2;         // 144,179,200 B
  const bool tier1 = ws_size >= need_full;
  const bool tier2 = ws_size >= need_hs1;

  if (tier2) {
    // ---------------- new bf16 path (tier 1 / tier 2) ----------------
    float* xg0      = out;                       // [3200,4096]
    u16*   x0w_bf   = (u16*)(out + 13200000);    // [64,2048]
    u16*   x0seq_bf = (u16*)(out + 13300000);    // [3200,2048]
    u16*   hs0_bf   = (u16*)(out + 16600000);    // [3200,2048]
    u16*   wih0a_bf = (u16*)(out + 20000000);    // [4096,2048]
    u16*   wih0b_bf = (u16*)(out + 24200000);
    u16*   wih1_bf  = (u16*)(out + 28400000);
    u16*   whh0_bf  = (u16*)(out + 32600000);
    u16*   whh1_bf  = (u16*)(out + 36800000);
    float* y_w      = out + 73800000;            // [64,4096]
    u16*   hbf_zero = (u16*)(out + 74100000);    // [64,2048]
    u16*   hbfA     = (u16*)(out + 74200000);
    u16*   hbfB     = (u16*)(out + 74300000);
    float* bias0p   = out + 74400000;
    float* bias1p   = out + 74410000;
    float* xg1      = out + 87560192;            // [3200,4096]

    u16*   decW_bf = (u16*)d_ws;                           // tier1 only
    u16*   hs1_bf  = (u16*)d_ws + (size_t)V_ * 2048;       // tier1 only
    float* hs1f    = (float*)d_ws;                         // tier2 only

    fill_zero<<<512, 256, 0, stream>>>(hL0, 2 * B_ * H_);
    fill_zero<<<256, 256, 0, stream>>>((float*)hbf_zero, 65536);
    bias_perm<<<16, 256, 0, stream>>>(b_ih0, b_hh0, bias0p);
    bias_perm<<<16, 256, 0, stream>>>(b_ih1, b_hh1, bias1p);

    gemm_nt<64, 64, 16, 4, 4><<<dim3(16, 1), 256, 0, stream>>>(
        emb, word, E_, w2h_W, E_, 0, w2h_b, nullptr, 0, -1, cL0, H_, B_, H_, E_);
    gemm_nt<64, 64, 16, 4, 4><<<dim3(16, 1), 256, 0, stream>>>(
        emb, word, E_, w2h_W, E_, 0, w2h_b, nullptr, 0, -1, cL1, H_, B_, H_, E_);

    // conversions
    conv_w<<<2048, 256, 0, stream>>>(W_ih0, 2 * E_, 0,  nullptr, 1, G_, wih0a_bf);
    conv_w<<<2048, 256, 0, stream>>>(W_ih0, 2 * E_, E_, nullptr, 1, G_, wih0b_bf);
    conv_w<<<2048, 256, 0, stream>>>(W_ih1, H_, 0, nullptr, 1, G_, wih1_bf);
    conv_w<<<2048, 256, 0, stream>>>(W_hh0, H_, 0, nullptr, 1, G_, whh0_bf);
    conv_w<<<2048, 256, 0, stream>>>(W_hh1, H_, 0, nullptr, 1, G_, whh1_bf);
    conv_w<<<32,   256, 0, stream>>>(emb, E_, 0, word, 0, B_, x0w_bf);
    conv_w<<<1600, 256, 0, stream>>>(emb, E_, 0, seq, 0, T_ * B_, x0seq_bf);
    if (tier1)
      conv_w<<<16000, 256, 0, stream>>>(dec_W, H_, 0, nullptr, 0, V_, decW_bf);

    // y_w = word_emb @ Wih0[:, :E]^T + bias0p
    gemm_bt<<<32, 256, 0, stream>>>(x0w_bf, B_, wih0a_bf, bias0p,
                                    nullptr, 0, -1, y_w, G_, G_, 32);
    // xg0 = seq_emb @ Wih0[:, E:]^T + y_w[b]
    gemm_bt<<<800, 256, 0, stream>>>(x0seq_bf, T_ * B_, wih0b_bf, nullptr,
                                     y_w, G_, 63, xg0, G_, G_, 32);

    for (int t = 0; t < T_; ++t) {
      const u16* hp = t ? hs0_bf + (size_t)(t - 1) * B_ * 2048 : hbf_zero;
      rnn_step<false><<<64, 256, 0, stream>>>(
          hp, whh0_bf, xg0 + (size_t)t * B_ * G_, cL0, hL0,
          hs0_bf + (size_t)t * B_ * 2048, nullptr);
    }

    // xg1 = hs0 @ Wih1^T + bias1p
    gemm_bt<<<800, 256, 0, stream>>>(hs0_bf, T_ * B_, wih1_bf, bias1p,
                                     nullptr, 0, -1, xg1, G_, G_, 32);

    if (tier1) {
      for (int t = 0; t < T_; ++t) {
        const u16* hp = t ? hs1_bf + (size_t)(t - 1) * B_ * 2048 : hbf_zero;
        rnn_step<false><<<64, 256, 0, stream>>>(
            hp, whh1_bf, xg1 + (size_t)t * B_ * G_, cL1, hL1,
            hs1_bf + (size_t)t * B_ * 2048, nullptr);
      }
      gemm_bt<<<6250, 256, 0, stream>>>(hs1_bf, T_ * B_, decW_bf, dec_b,
                                        nullptr, 0, -1, out, V_, V_, 250);
    } else {
      for (int t = 0; t < T_; ++t) {
        const u16* hp = t ? ((t & 1) ? hbfA : hbfB) : hbf_zero;
        u16* ho = (t & 1) ? hbfB : hbfA;
        rnn_step<true><<<64, 256, 0, stream>>>(
            hp, whh1_bf, xg1 + (size_t)t * B_ * G_, cL1, hL1, ho,
            hs1f + (size_t)t * B_ * H_);
      }
      gemm_sp<false, false><<<6250, 256, 0, stream>>>(
          hs1f, nullptr, H_, dec_W, H_, 0, dec_b, nullptr, 0, -1,
          out, V_, T_ * B_, V_, H_, 250);
    }
  } else {
    // ---------------- tier 3: legacy round-3 path (zero ws) ----------------
    float* xg0    = out;
    float* part   = out + 14000000;
    float* hs0    = out + 20000000;
    float* xg1    = out + 87560192;
    float* bias0c = out + 100700000;
    float* bias1c = out + 100704096;
    float* y_w    = out + 100708192;

    fill_zero<<<512, 256, 0, stream>>>(hL0, 2 * B_ * H_);
    vec_add<<<16, 256, 0, stream>>>(bias0c, b_ih0, b_hh0, G_);
    vec_add<<<16, 256, 0, stream>>>(bias1c, b_ih1, b_hh1, G_);
    gemm_nt<64, 64, 16, 4, 4><<<dim3(16, 1), 256, 0, stream>>>(
        emb, word, E_, w2h_W, E_, 0, w2h_b, nullptr, 0, -1, cL0, H_, B_, H_, E_);
    gemm_nt<64, 64, 16, 4, 4><<<dim3(16, 1), 256, 0, stream>>>(
        emb, word, E_, w2h_W, E_, 0, w2h_b, nullptr, 0, -1, cL1, H_, B_, H_, E_);
    gemm_sp<true, true><<<32, 256, 0, stream>>>(
        emb, word, E_, W_ih0, 2 * E_, 0, bias0c, nullptr, 0, -1,
        y_w, G_, B_, G_, E_, 32);
    gemm_sp<true, true><<<800, 256, 0, stream>>>(
        emb, seq, E_, W_ih0, 2 * E_, E_, nullptr, y_w, G_, 63,
        xg0, G_, T_ * B_, G_, E_, 32);
    for (int t = 0; t < T_; ++t) {
      rnn_part<<<dim3(64, 8), 256, 0, stream>>>(hL0, W_hh0, part);
      rnn_cell<<<256, 256, 0, stream>>>(part, xg0 + (size_t)t * B_ * G_,
                                        cL0, hL0, hs0 + (size_t)t * B_ * H_);
    }
    gemm_sp<false, true><<<800, 256, 0, stream>>>(
        hs0, nullptr, H_, W_ih1, H_, 0, bias1c, nullptr, 0, -1,
        xg1, G_, T_ * B_, G_, H_, 32);
    for (int t = 0; t < T_; ++t) {
      rnn_part<<<dim3(64, 8), 256, 0, stream>>>(hL1, W_hh1, part);
      rnn_cell<<<256, 256, 0, stream>>>(part, xg1 + (size_t)t * B_ * G_,
                                        cL1, hL1, nullptr);
      gemm_sp<false, false><<<250, 256, 0, stream>>>(
          hL1, nullptr, H_, dec_W, H_, 0, dec_b, nullptr, 0, -1,
          out + (size_t)t * B_ * V_, V_, B_, V_, H_, 250);
    }
  }
}